// Round 8
// baseline (589.185 us; speedup 1.0000x reference)
//
#include <hip/hip_runtime.h>

// OrthogonalAddTSU: sequential scan over S steps, carry h:(B,H).
// Per step: cos = <h,s>/max(|h||s|,eps); h = clip(h + (s - h*cos)*m, -1, 1).
// B=64, H=1024, S=512.
//
// Round-8 structure: TWO INDEPENDENT BATCH CHAINS PER WAVE.
//  Evidence: R4/R7 measure a constant ~6-8 cy per VALU instruction on a
//  lone wave across totally different structures (R1 160 inst/step->1270cy,
//  R2 117->853, R7 138->835). Memory pipelining (R4 +4%), LDS wave-split
//  (R5 regress), I$ (R7 neutral) are all eliminated. The wall is lone-wave
//  instruction throughput: dependency/hazard stalls with nothing to fill
//  them, or a hard single-wave issue cadence.
//  This round: 32 blocks x 64 threads; each wave scans batches b and b+32
//  INTERLEAVED at instruction level. Chains are independent -> chain B's
//  ops fill chain A's stall slots (no exchange, unlike R5). If stall-bound:
//  up to 2x. If cadence-bound: neutral -> proves inst-count is the only
//  lever (packed-FP32 next).
//  - 2-step groups via dwordx2 loads (keeps total VGPR ~205 allocatable:
//    2 batches x 2 ping-pong bufs x 16 rows x 2 regs = 128 buffer regs).
//  - Reductions: 4-chain interleaved DPP butterflies (dotA,hhA,dotB,hhB)
//    per step; per-group |s|^2 likewise 4 chains (2 steps x 2 batches).
//  - Masks bit-packed (R7 scheme): ballot -> lane-select into VGPRs;
//    per-iter dynamic readlanes; per-step SALU bit test; branchless step.
//  - All global loads volatile-asm; waits are operand-tied s_waitcnt
//    vmcnt(32) (the 32 newest outstanding = the two in-flight pong groups).

#define NB 32
#define NH 1024
#define NS 512
#define EL 16

typedef float v4f __attribute__((ext_vector_type(4)));
typedef float v2f __attribute__((ext_vector_type(2)));

template <int CTRL>
__device__ __forceinline__ float dpp_add(float x) {
  int s = __builtin_amdgcn_update_dpp(0, __builtin_bit_cast(int, x), CTRL, 0xf,
                                      0xf, true);
  return x + __builtin_bit_cast(float, s);
}

__device__ __forceinline__ float readlane_f(float v, int lane) {
  return __builtin_bit_cast(
      float, __builtin_amdgcn_readlane(__builtin_bit_cast(int, v), lane));
}

// 4 interleaved 64-lane butterfly chains; results broadcast via readlane 63.
__device__ __forceinline__ void wave_sum4(float& a, float& b, float& c,
                                          float& d) {
  a = dpp_add<0x111>(a); b = dpp_add<0x111>(b); c = dpp_add<0x111>(c); d = dpp_add<0x111>(d);
  a = dpp_add<0x112>(a); b = dpp_add<0x112>(b); c = dpp_add<0x112>(c); d = dpp_add<0x112>(d);
  a = dpp_add<0x114>(a); b = dpp_add<0x114>(b); c = dpp_add<0x114>(c); d = dpp_add<0x114>(d);
  a = dpp_add<0x118>(a); b = dpp_add<0x118>(b); c = dpp_add<0x118>(c); d = dpp_add<0x118>(d);
  a = dpp_add<0x142>(a); b = dpp_add<0x142>(b); c = dpp_add<0x142>(c); d = dpp_add<0x142>(d);
  a = dpp_add<0x143>(a); b = dpp_add<0x143>(b); c = dpp_add<0x143>(c); d = dpp_add<0x143>(d);
  a = readlane_f(a, 63);
  b = readlane_f(b, 63);
  c = readlane_f(c, 63);
  d = readlane_f(d, 63);
}

// volatile asm loads: cannot be sunk/reordered vs other volatile asm.
#define GLD4(dst, p, OFFSTR)                                   \
  asm volatile("global_load_dwordx4 %0, %1, off" OFFSTR        \
               : "=v"(dst)                                     \
               : "v"(p))
#define GLD2(dst, p, OFFSTR)                                   \
  asm volatile("global_load_dwordx2 %0, %1, off" OFFSTR        \
               : "=v"(dst)                                     \
               : "v"(p))
#define GLD1(dst, p)                                           \
  asm volatile("global_load_dword %0, %1, off" : "=v"(dst) : "v"(p))

// Issue one 2-step group for one batch: 16 rows x 8B; advance pointers.
// Pointers biased +2 rows: rows at 13-bit-signed offsets -4096..+2048.
#define ISSUE16_2(buf, q0, q1, q2, q3)     \
  do {                                     \
    GLD2(buf[0], q0, " offset:-4096");     \
    GLD2(buf[1], q0, " offset:-2048");     \
    GLD2(buf[2], q0, "");                  \
    GLD2(buf[3], q0, " offset:2048");      \
    GLD2(buf[4], q1, " offset:-4096");     \
    GLD2(buf[5], q1, " offset:-2048");     \
    GLD2(buf[6], q1, "");                  \
    GLD2(buf[7], q1, " offset:2048");      \
    GLD2(buf[8], q2, " offset:-4096");     \
    GLD2(buf[9], q2, " offset:-2048");     \
    GLD2(buf[10], q2, "");                 \
    GLD2(buf[11], q2, " offset:2048");     \
    GLD2(buf[12], q3, " offset:-4096");    \
    GLD2(buf[13], q3, " offset:-2048");    \
    GLD2(buf[14], q3, "");                 \
    GLD2(buf[15], q3, " offset:2048");     \
    q0 += 2; q1 += 2; q2 += 2; q3 += 2;    \
  } while (0)

// Wait until <=N VMEM loads outstanding; tie buffer regs (retire in order).
#define WAITPIN2(buf, N)                                            \
  do {                                                              \
    asm volatile("s_waitcnt vmcnt(" N ")"                           \
                 : "+v"(buf[0]), "+v"(buf[1]), "+v"(buf[2]),        \
                   "+v"(buf[3]), "+v"(buf[4]), "+v"(buf[5]),        \
                   "+v"(buf[6]), "+v"(buf[7]));                     \
    asm volatile("s_waitcnt vmcnt(" N ")"                           \
                 : "+v"(buf[8]), "+v"(buf[9]), "+v"(buf[10]),       \
                   "+v"(buf[11]), "+v"(buf[12]), "+v"(buf[13]),     \
                   "+v"(buf[14]), "+v"(buf[15]));                   \
  } while (0)

__global__ __launch_bounds__(64, 1) void otsu_scan_kernel(
    const float* __restrict__ tree,   // (B,H)
    const float* __restrict__ seq,    // (B,H,S)
    const float* __restrict__ mask,   // (B,S)
    float* __restrict__ out) {        // (B,H)
  const int b1 = blockIdx.x;        // chain A batch
  const int b2 = blockIdx.x + 32;   // chain B batch
  const int lane = threadIdx.x;     // 0..63

  // --- initial h for both chains + masks, via asm + full drain ---
  const float* hrowA = tree + b1 * NH + lane * EL;
  const float* hrowB = tree + b2 * NH + lane * EL;
  v4f hvA[4], hvB[4];
  GLD4(hvA[0], hrowA, "");
  GLD4(hvA[1], hrowA, " offset:16");
  GLD4(hvA[2], hrowA, " offset:32");
  GLD4(hvA[3], hrowA, " offset:48");
  GLD4(hvB[0], hrowB, "");
  GLD4(hvB[1], hrowB, " offset:16");
  GLD4(hvB[2], hrowB, " offset:32");
  GLD4(hvB[3], hrowB, " offset:48");
  float m8A[8], m8B[8];
  {
    const float* mpA = mask + b1 * NS + lane;
    const float* mpB = mask + b2 * NS + lane;
#pragma unroll
    for (int k = 0; k < 8; ++k) {
      GLD1(m8A[k], mpA + 64 * k);
      GLD1(m8B[k], mpB + 64 * k);
    }
  }
  asm volatile("s_waitcnt vmcnt(0)"
               : "+v"(hvA[0]), "+v"(hvA[1]), "+v"(hvA[2]), "+v"(hvA[3]),
                 "+v"(hvB[0]), "+v"(hvB[1]), "+v"(hvB[2]), "+v"(hvB[3]));
  asm volatile("s_waitcnt vmcnt(0)"
               : "+v"(m8A[0]), "+v"(m8A[1]), "+v"(m8A[2]), "+v"(m8A[3]),
                 "+v"(m8A[4]), "+v"(m8A[5]), "+v"(m8A[6]), "+v"(m8A[7]));
  asm volatile("s_waitcnt vmcnt(0)"
               : "+v"(m8B[0]), "+v"(m8B[1]), "+v"(m8B[2]), "+v"(m8B[3]),
                 "+v"(m8B[4]), "+v"(m8B[5]), "+v"(m8B[6]), "+v"(m8B[7]));

  float hA[EL], hB[EL];
#pragma unroll
  for (int k = 0; k < 4; ++k) {
    hA[4 * k + 0] = hvA[k].x; hA[4 * k + 1] = hvA[k].y;
    hA[4 * k + 2] = hvA[k].z; hA[4 * k + 3] = hvA[k].w;
    hB[4 * k + 0] = hvB[k].x; hB[4 * k + 1] = hvB[k].y;
    hB[4 * k + 2] = hvB[k].z; hB[4 * k + 3] = hvB[k].w;
  }

  // --- bit-pack masks (R7 scheme, writelane builtin unavailable) ---
  int vloA = 0, vhiA = 0, vloB = 0, vhiB = 0;
#pragma unroll
  for (int k = 0; k < 8; ++k) {
    unsigned long long wA = __ballot(m8A[k] != 0.0f);
    unsigned long long wB = __ballot(m8B[k] != 0.0f);
    vloA = (lane == k) ? (int)(unsigned)(wA & 0xffffffffull) : vloA;
    vhiA = (lane == k) ? (int)(unsigned)(wA >> 32) : vhiA;
    vloB = (lane == k) ? (int)(unsigned)(wB & 0xffffffffull) : vloB;
    vhiB = (lane == k) ? (int)(unsigned)(wB >> 32) : vhiB;
  }

  // seq row-base pointers, biased +2 rows (see ISSUE16_2)
  const float* sA = seq + (size_t)b1 * NH * NS + (size_t)(lane * EL) * NS;
  const float* sB = seq + (size_t)b2 * NH * NS + (size_t)(lane * EL) * NS;
  const float* pA0 = sA + 2 * NS;
  const float* pA1 = sA + 6 * NS;
  const float* pA2 = sA + 10 * NS;
  const float* pA3 = sA + 14 * NS;
  const float* pB0 = sB + 2 * NS;
  const float* pB1 = sB + 6 * NS;
  const float* pB2 = sB + 10 * NS;
  const float* pB3 = sB + 14 * NS;

  v2f A1[16], A2[16], B1[16], B2[16];

  // Process one 2-step group for BOTH chains, instruction-interleaved.
  // bb = bit index of step j=0 within mask words mwA/mwB.
  auto process2 = [&](const v2f* bA, const v2f* bB, unsigned long long mwA,
                      unsigned long long mwB, int bb) {
    // group |s|^2: 4 chains (2 steps x 2 batches)
    float qA0 = 0.f, qA1 = 0.f, rA0 = 0.f, rA1 = 0.f;
    float qB0 = 0.f, qB1 = 0.f, rB0 = 0.f, rB1 = 0.f;
#pragma unroll
    for (int i = 0; i < EL; i += 2) {
      qA0 = fmaf(bA[i][0], bA[i][0], qA0);
      qA1 = fmaf(bA[i + 1][0], bA[i + 1][0], qA1);
      rA0 = fmaf(bA[i][1], bA[i][1], rA0);
      rA1 = fmaf(bA[i + 1][1], bA[i + 1][1], rA1);
      qB0 = fmaf(bB[i][0], bB[i][0], qB0);
      qB1 = fmaf(bB[i + 1][0], bB[i + 1][0], qB1);
      rB0 = fmaf(bB[i][1], bB[i][1], rB0);
      rB1 = fmaf(bB[i + 1][1], bB[i + 1][1], rB1);
    }
    float s2A[2], s2B[2];
    s2A[0] = qA0 + qA1;
    s2A[1] = rA0 + rA1;
    s2B[0] = qB0 + qB1;
    s2B[1] = rB0 + rB1;
    wave_sum4(s2A[0], s2A[1], s2B[0], s2B[1]);

#pragma unroll
    for (int j = 0; j < 2; ++j) {
      const float mA = ((mwA >> (bb + j)) & 1ull) ? 1.0f : 0.0f;
      const float mB = ((mwB >> (bb + j)) & 1ull) ? 1.0f : 0.0f;
      float dA0 = 0.f, dA1 = 0.f, dA2 = 0.f, dA3 = 0.f;
      float eA0 = 0.f, eA1 = 0.f, eA2 = 0.f, eA3 = 0.f;
      float dB0 = 0.f, dB1 = 0.f, dB2 = 0.f, dB3 = 0.f;
      float eB0 = 0.f, eB1 = 0.f, eB2 = 0.f, eB3 = 0.f;
#pragma unroll
      for (int i = 0; i < EL; i += 4) {
        dA0 = fmaf(hA[i + 0], bA[i + 0][j], dA0);
        eA0 = fmaf(hA[i + 0], hA[i + 0], eA0);
        dA1 = fmaf(hA[i + 1], bA[i + 1][j], dA1);
        eA1 = fmaf(hA[i + 1], hA[i + 1], eA1);
        dA2 = fmaf(hA[i + 2], bA[i + 2][j], dA2);
        eA2 = fmaf(hA[i + 2], hA[i + 2], eA2);
        dA3 = fmaf(hA[i + 3], bA[i + 3][j], dA3);
        eA3 = fmaf(hA[i + 3], hA[i + 3], eA3);
        dB0 = fmaf(hB[i + 0], bB[i + 0][j], dB0);
        eB0 = fmaf(hB[i + 0], hB[i + 0], eB0);
        dB1 = fmaf(hB[i + 1], bB[i + 1][j], dB1);
        eB1 = fmaf(hB[i + 1], hB[i + 1], eB1);
        dB2 = fmaf(hB[i + 2], bB[i + 2][j], dB2);
        eB2 = fmaf(hB[i + 2], hB[i + 2], eB2);
        dB3 = fmaf(hB[i + 3], bB[i + 3][j], dB3);
        eB3 = fmaf(hB[i + 3], hB[i + 3], eB3);
      }
      float dotA = (dA0 + dA1) + (dA2 + dA3);
      float hhA = (eA0 + eA1) + (eA2 + eA3);
      float dotB = (dB0 + dB1) + (dB2 + dB3);
      float hhB = (eB0 + eB1) + (eB2 + eB3);
      wave_sum4(dotA, hhA, dotB, hhB);
      const float ppA = fmaxf(hhA * s2A[j], 1e-16f);  // denom^2 (eps 1e-8)
      const float ppB = fmaxf(hhB * s2B[j], 1e-16f);
      const float cA = dotA * __builtin_amdgcn_rsqf(ppA);
      const float cB = dotB * __builtin_amdgcn_rsqf(ppB);
      const float aA = fmaf(-cA, mA, 1.0f);  // m==0 -> a=1
      const float aB = fmaf(-cB, mB, 1.0f);
#pragma unroll
      for (int i = 0; i < EL; ++i) {
        const float smA = bA[i][j] * mA;  // m==0 -> 0
        const float smB = bB[i][j] * mB;
        hA[i] = __builtin_amdgcn_fmed3f(fmaf(hA[i], aA, smA), -1.0f, 1.0f);
        hB[i] = __builtin_amdgcn_fmed3f(fmaf(hB[i], aB, smB), -1.0f, 1.0f);
      }
    }
  };

  ISSUE16_2(A1, pA0, pA1, pA2, pA3);  // group 0, chain A
  ISSUE16_2(B1, pB0, pB1, pB2, pB3);  // group 0, chain B

  // ROLLED main loop: 127 iters x 2 groups (4 steps). Supergroup = 64 steps
  // = 16 iters; mask words rebuilt per iter via dynamic readlanes.
#pragma clang loop unroll(disable)
  for (int it = 0; it < 127; ++it) {
    const int sg = it >> 4;
    const unsigned int wloA = (unsigned)__builtin_amdgcn_readlane(vloA, sg);
    const unsigned int whiA = (unsigned)__builtin_amdgcn_readlane(vhiA, sg);
    const unsigned int wloB = (unsigned)__builtin_amdgcn_readlane(vloB, sg);
    const unsigned int whiB = (unsigned)__builtin_amdgcn_readlane(vhiB, sg);
    const unsigned long long mwA = ((unsigned long long)whiA << 32) | wloA;
    const unsigned long long mwB = ((unsigned long long)whiB << 32) | wloB;
    const int bb = (it & 15) * 4;  // bit of step 4it within supergroup
    ISSUE16_2(A2, pA0, pA1, pA2, pA3);  // group 2it+1
    ISSUE16_2(B2, pB0, pB1, pB2, pB3);
    WAITPIN2(A1, "32");  // 32 newest outstanding = A2+B2 -> A1,B1 done
    WAITPIN2(B1, "32");
    process2(A1, B1, mwA, mwB, bb);
    ISSUE16_2(A1, pA0, pA1, pA2, pA3);  // group 2it+2 (<= 254)
    ISSUE16_2(B1, pB0, pB1, pB2, pB3);
    WAITPIN2(A2, "32");
    WAITPIN2(B2, "32");
    process2(A2, B2, mwA, mwB, bb + 2);
  }
  {  // tail: groups 254 (ping) and 255 (pong) = steps 508..511
    const unsigned int wloA = (unsigned)__builtin_amdgcn_readlane(vloA, 7);
    const unsigned int whiA = (unsigned)__builtin_amdgcn_readlane(vhiA, 7);
    const unsigned int wloB = (unsigned)__builtin_amdgcn_readlane(vloB, 7);
    const unsigned int whiB = (unsigned)__builtin_amdgcn_readlane(vhiB, 7);
    const unsigned long long mwA = ((unsigned long long)whiA << 32) | wloA;
    const unsigned long long mwB = ((unsigned long long)whiB << 32) | wloB;
    ISSUE16_2(A2, pA0, pA1, pA2, pA3);  // group 255 (last; ends at row end)
    ISSUE16_2(B2, pB0, pB1, pB2, pB3);
    WAITPIN2(A1, "32");
    WAITPIN2(B1, "32");
    process2(A1, B1, mwA, mwB, 60);
    WAITPIN2(A2, "0");
    WAITPIN2(B2, "0");
    process2(A2, B2, mwA, mwB, 62);
  }

  // --- write final h for both chains ---
  float* oA = out + b1 * NH + lane * EL;
  float* oB = out + b2 * NH + lane * EL;
#pragma unroll
  for (int i = 0; i < 4; ++i) {
    v4f va = {hA[4 * i + 0], hA[4 * i + 1], hA[4 * i + 2], hA[4 * i + 3]};
    v4f vb = {hB[4 * i + 0], hB[4 * i + 1], hB[4 * i + 2], hB[4 * i + 3]};
    *(v4f*)(oA + 4 * i) = va;
    *(v4f*)(oB + 4 * i) = vb;
  }
}

extern "C" void kernel_launch(void* const* d_in, const int* in_sizes, int n_in,
                              void* d_out, int out_size, void* d_ws,
                              size_t ws_size, hipStream_t stream) {
  const float* tree = (const float*)d_in[0];  // (64,1024)
  const float* seq = (const float*)d_in[1];   // (64,1024,512)
  const float* mask = (const float*)d_in[2];  // (64,512)
  float* out = (float*)d_out;                 // (64,1024)
  otsu_scan_kernel<<<dim3(NB), dim3(64), 0, stream>>>(tree, seq, mask, out);
}